// Round 10
// baseline (193.000 us; speedup 1.0000x reference)
//
#include <hip/hip_runtime.h>
#include <hip/hip_bf16.h>

typedef __attribute__((ext_vector_type(8))) short short8;
typedef __attribute__((ext_vector_type(4))) float f32x4;

#define MFMA16(a, b, c) __builtin_amdgcn_mfma_f32_16x16x32_bf16((a), (b), (c), 0, 0, 0)

// scalar round-to-nearest-even f32 -> bf16 bits (proven rounds 1/3/6)
__device__ inline unsigned short f2bf(float f) {
    union { float f; unsigned int u; } v;
    v.f = f;
    unsigned int u = v.u;
    return (unsigned short)((u + 0x7fffu + ((u >> 16) & 1u)) >> 16);
}

// ---------------------------------------------------------------------------
// Wt[n][c] bf16, n in [0,192): 0..63 Wq (pre-scaled 1/8), 64..127 Wk, 128..191 Wv
// ---------------------------------------------------------------------------
__global__ __launch_bounds__(256) void prep_w(const float* __restrict__ Wq,
                                              const float* __restrict__ Wk,
                                              const float* __restrict__ Wv,
                                              unsigned short* __restrict__ Wt) {
    int idx = blockIdx.x * 256 + threadIdx.x;
    if (idx >= 192 * 1024) return;
    int n = idx >> 10;
    int c = idx & 1023;
    const float* W = (n < 64) ? Wq : ((n < 128) ? Wk : Wv);
    float v = W[c * 64 + (n & 63)];
    if (n < 64) v *= 0.125f;  // fold 1/sqrt(head_size) into Wq
    Wt[idx] = f2bf(v);
}

// ---------------------------------------------------------------------------
// proj3: N-split projection. grid = 3072 = 1024 row-tiles x 3 projections
// (tb fast, pj slow: the 3 readers of row-tile tb are bid {tb, tb+1024,
// tb+2048} -> same XCD since 1024%8==0 -> x re-reads are L2 hits).
// Block: 16 rows x 64 outputs; wave w owns one 16x16 tile (acc = 4 VGPRs).
// 12 blocks/CU -> occupancy capped only by the 32-waves/CU limit.
// ---------------------------------------------------------------------------
__global__ __launch_bounds__(256, 8) void proj3(const float* __restrict__ x,
                                                const unsigned short* __restrict__ Wt,
                                                unsigned short* __restrict__ Qs,
                                                unsigned short* __restrict__ Ks,
                                                unsigned short* __restrict__ Vt) {
    __shared__ unsigned short vt_l[64][16];  // used only by pj==2 blocks

    int bid = blockIdx.x;
    int tb = bid & 1023;
    int pj = bid >> 10;  // 0=Q, 1=K, 2=V
    int w = threadIdx.x >> 6;
    int lane = threadIdx.x & 63;
    int lr = lane & 15;
    int lg = lane >> 4;
    int t0 = tb * 16;
    int nb = pj * 64 + w * 16;  // wave's first global output col

    f32x4 acc = (f32x4){0.f, 0.f, 0.f, 0.f};
    const float* xrow = x + (size_t)(t0 + lr) * 1024 + lg * 8;
    const unsigned short* wrow = Wt + (size_t)(nb + lr) * 1024 + lg * 8;

    for (int c0 = 0; c0 < 1024; c0 += 32) {
        float4 xa = *(const float4*)(xrow + c0);
        float4 xb = *(const float4*)(xrow + c0 + 4);
        short8 b = *(const short8*)(wrow + c0);
        short8 a;
        a[0] = (short)f2bf(xa.x); a[1] = (short)f2bf(xa.y);
        a[2] = (short)f2bf(xa.z); a[3] = (short)f2bf(xa.w);
        a[4] = (short)f2bf(xb.x); a[5] = (short)f2bf(xb.y);
        a[6] = (short)f2bf(xb.z); a[7] = (short)f2bf(xb.w);
        acc = MFMA16(a, b, acc);
    }

    // D layout: col = lr (n within tile), row = lg*4 + r (t within tile)
    if (pj == 0) {
#pragma unroll
        for (int r = 0; r < 4; r++)
            Qs[(size_t)(t0 + lg * 4 + r) * 64 + w * 16 + lr] = f2bf(acc[r]);
    } else if (pj == 1) {
#pragma unroll
        for (int r = 0; r < 4; r++)
            Ks[(size_t)(t0 + lg * 4 + r) * 64 + w * 16 + lr] = f2bf(acc[r]);
    } else {
#pragma unroll
        for (int r = 0; r < 4; r++)
            vt_l[w * 16 + lr][lg * 4 + r] = f2bf(acc[r]);
        __syncthreads();
        int h = threadIdx.x >> 2;
        int part = threadIdx.x & 3;
        int b = t0 >> 12;
        int tt0 = t0 & 4095;
        uint2 val = *(const uint2*)&vt_l[h][part * 4];
        *(uint2*)(Vt + (size_t)b * 262144 + (size_t)h * 4096 + tt0 + part * 4) = val;
    }
}

// ---------------------------------------------------------------------------
// attn<NS>: causal flash attention, swapped QK^T (S^T = K*Q), QBLK=32 (2 q-
// subtiles), KVBLK=64, 1 wave/block, KV split into NS chunks.
// ---------------------------------------------------------------------------
#define SROW 72  // P-tile row stride in halfwords (144 B/row)

template <int NS>
__global__ __launch_bounds__(64) void attn(const unsigned short* __restrict__ Qs,
                                           const unsigned short* __restrict__ Ks,
                                           const unsigned short* __restrict__ Vt,
                                           float* __restrict__ out,
                                           float* __restrict__ accP,
                                           float* __restrict__ mP,
                                           float* __restrict__ lP) {
    __shared__ unsigned short pl[32 * SROW];  // 32 q-rows x 64 kv-cols

    const int ntasks = 512 * NS;
    int raw = ntasks - 1 - blockIdx.x;  // longest scans first
    int qt_g = raw / NS;
    int c = raw - qt_g * NS;
    int qt = qt_g >> 2;
    int b = qt_g & 3;
    int q0 = qt * 32;

    int lane = threadIdx.x;
    int lr = lane & 15;
    int lg = lane >> 4;

    const unsigned short* Qb = Qs + (size_t)b * 262144;
    const unsigned short* Kb = Ks + (size_t)b * 262144;
    const unsigned short* Vb = Vt + (size_t)b * 262144;

    short8 qf[2][2];
#pragma unroll
    for (int qs = 0; qs < 2; qs++)
#pragma unroll
        for (int kh = 0; kh < 2; kh++)
            qf[qs][kh] = *(const short8*)(Qb + (size_t)(q0 + qs * 16 + lr) * 64 +
                                          kh * 32 + lg * 8);

    f32x4 acc[4][2];  // [ht][qs]
#pragma unroll
    for (int i = 0; i < 4; i++)
#pragma unroll
        for (int qs = 0; qs < 2; qs++) acc[i][qs] = (f32x4){0.f, 0.f, 0.f, 0.f};
    float m[2] = {-1e30f, -1e30f}, l[2] = {0.f, 0.f};

    int nt = (q0 + 95) >> 6;  // ceil((q0+32)/64)
    int tb = (c * nt) / NS;
    int te = ((c + 1) * nt) / NS;

    for (int t64 = tb; t64 < te; ++t64) {
        int kv0 = t64 * 64;

        // ---- S^T = K Q : [64kv x 32q]; lane holds kv=t*16+lg*4+r, q=qs*16+lr
        f32x4 s[4][2];
#pragma unroll
        for (int t = 0; t < 4; t++) {
            const unsigned short* kp = Kb + (size_t)(kv0 + t * 16 + lr) * 64 + lg * 8;
            short8 k0 = *(const short8*)(kp);
            short8 k1 = *(const short8*)(kp + 32);
#pragma unroll
            for (int qs = 0; qs < 2; qs++) {
                f32x4 z = (f32x4){0.f, 0.f, 0.f, 0.f};
                z = MFMA16(k0, qf[qs][0], z);
                z = MFMA16(k1, qf[qs][1], z);
                s[t][qs] = z;
            }
        }

        // ---- issue V loads early (consumed after softmax) ----
        short8 vf[4][2];
#pragma unroll
        for (int ht = 0; ht < 4; ht++)
#pragma unroll
            for (int half = 0; half < 2; half++)
                vf[ht][half] = *(const short8*)(Vb + (size_t)(ht * 16 + lr) * 4096 +
                                                kv0 + half * 32 + lg * 8);

        // ---- causal mask (only the straddling tile needs it) ----
        if (kv0 + 63 > q0) {
#pragma unroll
            for (int t = 0; t < 4; t++)
#pragma unroll
                for (int qs = 0; qs < 2; qs++)
#pragma unroll
                    for (int r = 0; r < 4; r++) {
                        int kv = kv0 + t * 16 + lg * 4 + r;
                        if (kv > q0 + qs * 16 + lr) s[t][qs][r] = -1e30f;
                    }
        }

        // ---- online softmax: lane-local over 16 kv, 2 shuffles per reduce ----
        float mx[2] = {-1e30f, -1e30f};
#pragma unroll
        for (int t = 0; t < 4; t++)
#pragma unroll
            for (int qs = 0; qs < 2; qs++)
#pragma unroll
                for (int r = 0; r < 4; r++) mx[qs] = fmaxf(mx[qs], s[t][qs][r]);
        float alpha[2];
#pragma unroll
        for (int qs = 0; qs < 2; qs++) {
            mx[qs] = fmaxf(mx[qs], __shfl_xor(mx[qs], 16));
            mx[qs] = fmaxf(mx[qs], __shfl_xor(mx[qs], 32));
            float mn = fmaxf(m[qs], mx[qs]);
            alpha[qs] = __expf(m[qs] - mn);
            m[qs] = mn;
        }
        float ps[2] = {0.f, 0.f};
#pragma unroll
        for (int t = 0; t < 4; t++)
#pragma unroll
            for (int qs = 0; qs < 2; qs++)
#pragma unroll
                for (int r = 0; r < 4; r++) {
                    float e = __expf(s[t][qs][r] - m[qs]);
                    s[t][qs][r] = e;
                    ps[qs] += e;
                }
#pragma unroll
        for (int qs = 0; qs < 2; qs++) {
            ps[qs] += __shfl_xor(ps[qs], 16);
            ps[qs] += __shfl_xor(ps[qs], 32);
            l[qs] = l[qs] * alpha[qs] + ps[qs];
        }

        // ---- rescale O (row q = qs*16+lg*4+r needs alpha from lane lg*4+r) ----
        float ar[2][4];
#pragma unroll
        for (int qs = 0; qs < 2; qs++)
#pragma unroll
            for (int r = 0; r < 4; r++) ar[qs][r] = __shfl(alpha[qs], lg * 4 + r);
#pragma unroll
        for (int ht = 0; ht < 4; ht++)
#pragma unroll
            for (int qs = 0; qs < 2; qs++)
#pragma unroll
                for (int r = 0; r < 4; r++) acc[ht][qs][r] *= ar[qs][r];

        // ---- pack P -> LDS (transpose to A-fragment layout) ----
#pragma unroll
        for (int qs = 0; qs < 2; qs++)
#pragma unroll
            for (int t = 0; t < 4; t++) {
                uint2 uu;
                uu.x = (unsigned)f2bf(s[t][qs][0]) | ((unsigned)f2bf(s[t][qs][1]) << 16);
                uu.y = (unsigned)f2bf(s[t][qs][2]) | ((unsigned)f2bf(s[t][qs][3]) << 16);
                *(uint2*)&pl[(qs * 16 + lr) * SROW + t * 16 + lg * 4] = uu;
            }
        __syncthreads();
        short8 pa[2][2];
#pragma unroll
        for (int qs = 0; qs < 2; qs++)
#pragma unroll
            for (int half = 0; half < 2; half++)
                pa[qs][half] = *(const short8*)&pl[(qs * 16 + lr) * SROW +
                                                   half * 32 + lg * 8];

        // ---- O += P V ----
#pragma unroll
        for (int ht = 0; ht < 4; ht++)
#pragma unroll
            for (int qs = 0; qs < 2; qs++) {
                acc[ht][qs] = MFMA16(pa[qs][0], vf[ht][0], acc[ht][qs]);
                acc[ht][qs] = MFMA16(pa[qs][1], vf[ht][1], acc[ht][qs]);
            }
        __syncthreads();
    }

    if (NS == 1) {
        float rl[2][4];
#pragma unroll
        for (int qs = 0; qs < 2; qs++)
#pragma unroll
            for (int r = 0; r < 4; r++) rl[qs][r] = 1.0f / __shfl(l[qs], lg * 4 + r);
#pragma unroll
        for (int ht = 0; ht < 4; ht++)
#pragma unroll
            for (int qs = 0; qs < 2; qs++)
#pragma unroll
                for (int r = 0; r < 4; r++) {
                    size_t o = ((size_t)b * 4096 + q0 + qs * 16 + lg * 4 + r) * 64 +
                               ht * 16 + lr;
                    out[o] = acc[ht][qs][r] * rl[qs][r];
                }
    } else {
        int tidx = qt_g * NS + c;
        float* ap = accP + (size_t)tidx * 2048;
#pragma unroll
        for (int ht = 0; ht < 4; ht++)
#pragma unroll
            for (int qs = 0; qs < 2; qs++)
#pragma unroll
                for (int r = 0; r < 4; r++)
                    ap[(qs * 16 + lg * 4 + r) * 64 + ht * 16 + lr] = acc[ht][qs][r];
        if (lane < 16) {
#pragma unroll
            for (int qs = 0; qs < 2; qs++) {
                mP[tidx * 32 + qs * 16 + lane] = m[qs];
                lP[tidx * 32 + qs * 16 + lane] = l[qs];
            }
        }
    }
}

// ---------------------------------------------------------------------------
// combine<NS>: out[row][h] = sum_c e^{m_c-M} acc_c / sum_c e^{m_c-M} l_c
// ---------------------------------------------------------------------------
template <int NS>
__global__ __launch_bounds__(256) void combine(const float* __restrict__ accP,
                                               const float* __restrict__ mP,
                                               const float* __restrict__ lP,
                                               float* __restrict__ out) {
    int g = blockIdx.x * 256 + threadIdx.x;  // 0 .. 1M-1
    int h = g & 63;
    int row = g >> 6;       // b*4096 + t
    int b = row >> 12;
    int t = row & 4095;
    int qt = t >> 5;
    int qr = t & 31;
    int qt_g = qt * 4 + b;

    float mc[NS];
    float M = -1e30f;
#pragma unroll
    for (int c = 0; c < NS; c++) {
        mc[c] = mP[(qt_g * NS + c) * 32 + qr];
        M = fmaxf(M, mc[c]);
    }
    float num = 0.f, den = 0.f;
#pragma unroll
    for (int c = 0; c < NS; c++) {
        float wgt = __expf(mc[c] - M);
        den += wgt * lP[(qt_g * NS + c) * 32 + qr];
        num += wgt * accP[(size_t)(qt_g * NS + c) * 2048 + qr * 64 + h];
    }
    out[g] = num / den;
}

// ---------------------------------------------------------------------------
extern "C" void kernel_launch(void* const* d_in, const int* in_sizes, int n_in,
                              void* d_out, int out_size, void* d_ws, size_t ws_size,
                              hipStream_t stream) {
    const float* x  = (const float*)d_in[0];
    const float* Wq = (const float*)d_in[1];
    const float* Wk = (const float*)d_in[2];
    const float* Wv = (const float*)d_in[3];
    float* out = (float*)d_out;

    char* ws = (char*)d_ws;
    unsigned short* Qs = (unsigned short*)(ws);                   // 2 MB @ 0
    unsigned short* Ks = (unsigned short*)(ws + (2u << 20));      // 2 MB @ 2M
    unsigned short* Vt = (unsigned short*)(ws + (4u << 20));      // 2 MB @ 4M
    unsigned short* Wt = (unsigned short*)(ws + (6u << 20));      // 384 KB @ 6M
    float* accP = (float*)(ws + (8u << 20));                      // 16 MB @ 8M  (2048 tasks x 8KB)
    float* mP   = (float*)(ws + (24u << 20));                     // 256 KB @ 24M
    float* lP   = (float*)(ws + (24u << 20) + (256u << 10));      // 256 KB

    prep_w<<<768, 256, 0, stream>>>(Wq, Wk, Wv, Wt);
    proj3<<<3072, 256, 0, stream>>>(x, Wt, Qs, Ks, Vt);

    if (ws_size >= (25u << 20)) {
        attn<4><<<2048, 64, 0, stream>>>(Qs, Ks, Vt, out, accP, mP, lP);
        combine<4><<<4096, 256, 0, stream>>>(accP, mP, lP, out);
    } else {
        attn<1><<<512, 64, 0, stream>>>(Qs, Ks, Vt, out, accP, mP, lP);
    }
}

// Round 11
// 107.006 us; speedup vs baseline: 1.8036x; 1.8036x over previous
//
#include <hip/hip_runtime.h>
#include <hip/hip_bf16.h>

typedef __attribute__((ext_vector_type(8))) short short8;
typedef __attribute__((ext_vector_type(4))) float f32x4;

#define MFMA16(a, b, c) __builtin_amdgcn_mfma_f32_16x16x32_bf16((a), (b), (c), 0, 0, 0)

// async global->LDS, 16B per lane; dest is wave-uniform base + lane*16
typedef const __attribute__((address_space(1))) unsigned int* gas_t;
typedef __attribute__((address_space(3))) unsigned int* las_t;
#define GLDS16(g, l) __builtin_amdgcn_global_load_lds((gas_t)(g), (las_t)(l), 16, 0, 0)

// scalar round-to-nearest-even f32 -> bf16 bits (proven rounds 1/3/6)
__device__ inline unsigned short f2bf(float f) {
    union { float f; unsigned int u; } v;
    v.f = f;
    unsigned int u = v.u;
    return (unsigned short)((u + 0x7fffu + ((u >> 16) & 1u)) >> 16);
}

// ---------------------------------------------------------------------------
// Wt[n][c] bf16, n in [0,192): 0..63 Wq (pre-scaled 1/8), 64..127 Wk, 128..191 Wv
// ---------------------------------------------------------------------------
__global__ __launch_bounds__(256) void prep_w(const float* __restrict__ Wq,
                                              const float* __restrict__ Wk,
                                              const float* __restrict__ Wv,
                                              unsigned short* __restrict__ Wt) {
    int idx = blockIdx.x * 256 + threadIdx.x;
    if (idx >= 192 * 1024) return;
    int n = idx >> 10;
    int c = idx & 1023;
    const float* W = (n < 64) ? Wq : ((n < 128) ? Wk : Wv);
    float v = W[c * 64 + (n & 63)];
    if (n < 64) v *= 0.125f;  // fold 1/sqrt(head_size) into Wq
    Wt[idx] = f2bf(v);
}

// ---------------------------------------------------------------------------
// projt: m97-pattern tiled projection. 512 blocks x 4 waves; tile 32 rows x
// 192 cols; BK=64. x staged f32 into double-buffered LDS via global_load_lds
// (issue pinned by HW side effect -> latency hides under compute); W-fragments
// register-loaded from L2 (384 KB resident). x-tile 16B slots XOR-swizzled
// (slot ^ (row&7)) on BOTH the global source and the ds_read -> conflict-free.
// Wave (wr,wc): rows [wr*16,+16), cols [wc*96,+96) = 6 accumulators.
// ---------------------------------------------------------------------------
__global__ __launch_bounds__(256, 4) void projt(const float* __restrict__ x,
                                                const unsigned short* __restrict__ Wt,
                                                unsigned short* __restrict__ Qs,
                                                unsigned short* __restrict__ Ks,
                                                unsigned short* __restrict__ Vt) {
    __shared__ __align__(16) float xbuf[2][32 * 64];       // 16 KB dbuf x tile
    __shared__ __align__(16) unsigned short vt_l[64][32];  // 4 KB V transpose

    const int tid = threadIdx.x;
    const int w = tid >> 6;
    const int lane = tid & 63;
    const int lr = lane & 15;
    const int lg = lane >> 4;
    const int wr = w >> 1;
    const int wc = w & 1;
    const int t0 = blockIdx.x * 32;

    f32x4 acc[6];
#pragma unroll
    for (int i = 0; i < 6; i++) acc[i] = (f32x4){0.f, 0.f, 0.f, 0.f};

    const unsigned short* wbase = Wt + (size_t)(wc * 96 + lr) * 1024 + lg * 8;

    // wave w stages rows [w*8, w*8+8) of the 32x64-f32 tile (2 calls x 1KB)
    // LDS layout: row-major, 256B/row; 16B slot s holds k-chunk (s ^ (row&7)).
#define STAGE_X(buf, c0)                                                      \
    {                                                                         \
        _Pragma("unroll")                                                     \
        for (int p = 0; p < 2; p++) {                                         \
            int row = w * 8 + p * 4 + (lane >> 4);                            \
            int sw = (lane & 15) ^ (row & 7);                                 \
            const float* src = x + (size_t)(t0 + row) * 1024 + (c0) + sw * 4; \
            float* dst = &xbuf[buf][(w * 8 + p * 4) * 64]; /* wave-uniform */ \
            GLDS16(src, dst);                                                 \
        }                                                                     \
    }

    STAGE_X(0, 0);
    __syncthreads();

    int cur = 0;
    for (int t = 0; t < 16; ++t) {
        if (t < 15) STAGE_X(cur ^ 1, (t + 1) * 64);

        const int c0 = t * 64;
        const char* xb = (const char*)&xbuf[cur][0];
        const int row = wr * 16 + lr;
#pragma unroll
        for (int h = 0; h < 2; h++) {
            short8 bfr[6];
#pragma unroll
            for (int nt = 0; nt < 6; nt++)
                bfr[nt] = *(const short8*)(wbase + (size_t)nt * 16384 + c0 + h * 32);
            int sbase = h * 8 + lg * 2;
            float4 a0 = *(const float4*)(xb + row * 256 + ((sbase) ^ (row & 7)) * 16);
            float4 a1 = *(const float4*)(xb + row * 256 + ((sbase + 1) ^ (row & 7)) * 16);
            short8 a;
            a[0] = (short)f2bf(a0.x); a[1] = (short)f2bf(a0.y);
            a[2] = (short)f2bf(a0.z); a[3] = (short)f2bf(a0.w);
            a[4] = (short)f2bf(a1.x); a[5] = (short)f2bf(a1.y);
            a[6] = (short)f2bf(a1.z); a[7] = (short)f2bf(a1.w);
#pragma unroll
            for (int nt = 0; nt < 6; nt++) acc[nt] = MFMA16(a, bfr[nt], acc[nt]);
        }
        __syncthreads();  // drains staging vmcnt + LDS reads; swap buffers
        cur ^= 1;
    }

    // epilogue: D col = lr -> n, row = lg*4+r -> t
#pragma unroll
    for (int nt = 0; nt < 6; nt++) {
        int n = wc * 96 + nt * 16 + lr;
#pragma unroll
        for (int r = 0; r < 4; r++) {
            int lrow = wr * 16 + lg * 4 + r;
            float v = acc[nt][r];
            if (n < 64) {
                Qs[(size_t)(t0 + lrow) * 64 + n] = f2bf(v);
            } else if (n < 128) {
                Ks[(size_t)(t0 + lrow) * 64 + (n - 64)] = f2bf(v);
            } else {
                vt_l[n - 128][lrow] = f2bf(v);
            }
        }
    }
    __syncthreads();
    // cooperative coalesced V^T store: 64 h-rows x 32 t-cols
    {
        int h = tid >> 2;
        int part = tid & 3;
        int b = t0 >> 12;
        int tt0 = t0 & 4095;
        uint4 val = *(const uint4*)&vt_l[h][part * 8];
        *(uint4*)(Vt + (size_t)b * 262144 + (size_t)h * 4096 + tt0 + part * 8) = val;
    }
}

// ---------------------------------------------------------------------------
// attn<NS>: causal flash attention, swapped QK^T (S^T = K*Q), QBLK=32 (2 q-
// subtiles), KVBLK=64, 1 wave/block, KV split into NS chunks.
// ---------------------------------------------------------------------------
#define SROW 72  // P-tile row stride in halfwords (144 B/row)

template <int NS>
__global__ __launch_bounds__(64) void attn(const unsigned short* __restrict__ Qs,
                                           const unsigned short* __restrict__ Ks,
                                           const unsigned short* __restrict__ Vt,
                                           float* __restrict__ out,
                                           float* __restrict__ accP,
                                           float* __restrict__ mP,
                                           float* __restrict__ lP) {
    __shared__ unsigned short pl[32 * SROW];  // 32 q-rows x 64 kv-cols

    const int ntasks = 512 * NS;
    int raw = ntasks - 1 - blockIdx.x;  // longest scans first
    int qt_g = raw / NS;
    int c = raw - qt_g * NS;
    int qt = qt_g >> 2;
    int b = qt_g & 3;
    int q0 = qt * 32;

    int lane = threadIdx.x;
    int lr = lane & 15;
    int lg = lane >> 4;

    const unsigned short* Qb = Qs + (size_t)b * 262144;
    const unsigned short* Kb = Ks + (size_t)b * 262144;
    const unsigned short* Vb = Vt + (size_t)b * 262144;

    short8 qf[2][2];
#pragma unroll
    for (int qs = 0; qs < 2; qs++)
#pragma unroll
        for (int kh = 0; kh < 2; kh++)
            qf[qs][kh] = *(const short8*)(Qb + (size_t)(q0 + qs * 16 + lr) * 64 +
                                          kh * 32 + lg * 8);

    f32x4 acc[4][2];  // [ht][qs]
#pragma unroll
    for (int i = 0; i < 4; i++)
#pragma unroll
        for (int qs = 0; qs < 2; qs++) acc[i][qs] = (f32x4){0.f, 0.f, 0.f, 0.f};
    float m[2] = {-1e30f, -1e30f}, l[2] = {0.f, 0.f};

    int nt = (q0 + 95) >> 6;  // ceil((q0+32)/64)
    int tb = (c * nt) / NS;
    int te = ((c + 1) * nt) / NS;

    for (int t64 = tb; t64 < te; ++t64) {
        int kv0 = t64 * 64;

        // ---- S^T = K Q : [64kv x 32q]; lane holds kv=t*16+lg*4+r, q=qs*16+lr
        f32x4 s[4][2];
#pragma unroll
        for (int t = 0; t < 4; t++) {
            const unsigned short* kp = Kb + (size_t)(kv0 + t * 16 + lr) * 64 + lg * 8;
            short8 k0 = *(const short8*)(kp);
            short8 k1 = *(const short8*)(kp + 32);
#pragma unroll
            for (int qs = 0; qs < 2; qs++) {
                f32x4 z = (f32x4){0.f, 0.f, 0.f, 0.f};
                z = MFMA16(k0, qf[qs][0], z);
                z = MFMA16(k1, qf[qs][1], z);
                s[t][qs] = z;
            }
        }

        // ---- issue V loads early (consumed after softmax) ----
        short8 vf[4][2];
#pragma unroll
        for (int ht = 0; ht < 4; ht++)
#pragma unroll
            for (int half = 0; half < 2; half++)
                vf[ht][half] = *(const short8*)(Vb + (size_t)(ht * 16 + lr) * 4096 +
                                                kv0 + half * 32 + lg * 8);

        // ---- causal mask (only the straddling tile needs it) ----
        if (kv0 + 63 > q0) {
#pragma unroll
            for (int t = 0; t < 4; t++)
#pragma unroll
                for (int qs = 0; qs < 2; qs++)
#pragma unroll
                    for (int r = 0; r < 4; r++) {
                        int kv = kv0 + t * 16 + lg * 4 + r;
                        if (kv > q0 + qs * 16 + lr) s[t][qs][r] = -1e30f;
                    }
        }

        // ---- online softmax: lane-local over 16 kv, 2 shuffles per reduce ----
        float mx[2] = {-1e30f, -1e30f};
#pragma unroll
        for (int t = 0; t < 4; t++)
#pragma unroll
            for (int qs = 0; qs < 2; qs++)
#pragma unroll
                for (int r = 0; r < 4; r++) mx[qs] = fmaxf(mx[qs], s[t][qs][r]);
        float alpha[2];
#pragma unroll
        for (int qs = 0; qs < 2; qs++) {
            mx[qs] = fmaxf(mx[qs], __shfl_xor(mx[qs], 16));
            mx[qs] = fmaxf(mx[qs], __shfl_xor(mx[qs], 32));
            float mn = fmaxf(m[qs], mx[qs]);
            alpha[qs] = __expf(m[qs] - mn);
            m[qs] = mn;
        }
        float ps[2] = {0.f, 0.f};
#pragma unroll
        for (int t = 0; t < 4; t++)
#pragma unroll
            for (int qs = 0; qs < 2; qs++)
#pragma unroll
                for (int r = 0; r < 4; r++) {
                    float e = __expf(s[t][qs][r] - m[qs]);
                    s[t][qs][r] = e;
                    ps[qs] += e;
                }
#pragma unroll
        for (int qs = 0; qs < 2; qs++) {
            ps[qs] += __shfl_xor(ps[qs], 16);
            ps[qs] += __shfl_xor(ps[qs], 32);
            l[qs] = l[qs] * alpha[qs] + ps[qs];
        }

        // ---- rescale O (row q = qs*16+lg*4+r needs alpha from lane lg*4+r) ----
        float ar[2][4];
#pragma unroll
        for (int qs = 0; qs < 2; qs++)
#pragma unroll
            for (int r = 0; r < 4; r++) ar[qs][r] = __shfl(alpha[qs], lg * 4 + r);
#pragma unroll
        for (int ht = 0; ht < 4; ht++)
#pragma unroll
            for (int qs = 0; qs < 2; qs++)
#pragma unroll
                for (int r = 0; r < 4; r++) acc[ht][qs][r] *= ar[qs][r];

        // ---- pack P -> LDS (transpose to A-fragment layout) ----
#pragma unroll
        for (int qs = 0; qs < 2; qs++)
#pragma unroll
            for (int t = 0; t < 4; t++) {
                uint2 uu;
                uu.x = (unsigned)f2bf(s[t][qs][0]) | ((unsigned)f2bf(s[t][qs][1]) << 16);
                uu.y = (unsigned)f2bf(s[t][qs][2]) | ((unsigned)f2bf(s[t][qs][3]) << 16);
                *(uint2*)&pl[(qs * 16 + lr) * SROW + t * 16 + lg * 4] = uu;
            }
        __syncthreads();
        short8 pa[2][2];
#pragma unroll
        for (int qs = 0; qs < 2; qs++)
#pragma unroll
            for (int half = 0; half < 2; half++)
                pa[qs][half] = *(const short8*)&pl[(qs * 16 + lr) * SROW +
                                                   half * 32 + lg * 8];

        // ---- O += P V ----
#pragma unroll
        for (int ht = 0; ht < 4; ht++)
#pragma unroll
            for (int qs = 0; qs < 2; qs++) {
                acc[ht][qs] = MFMA16(pa[qs][0], vf[ht][0], acc[ht][qs]);
                acc[ht][qs] = MFMA16(pa[qs][1], vf[ht][1], acc[ht][qs]);
            }
        __syncthreads();
    }

    if (NS == 1) {
        float rl[2][4];
#pragma unroll
        for (int qs = 0; qs < 2; qs++)
#pragma unroll
            for (int r = 0; r < 4; r++) rl[qs][r] = 1.0f / __shfl(l[qs], lg * 4 + r);
#pragma unroll
        for (int ht = 0; ht < 4; ht++)
#pragma unroll
            for (int qs = 0; qs < 2; qs++)
#pragma unroll
                for (int r = 0; r < 4; r++) {
                    size_t o = ((size_t)b * 4096 + q0 + qs * 16 + lg * 4 + r) * 64 +
                               ht * 16 + lr;
                    out[o] = acc[ht][qs][r] * rl[qs][r];
                }
    } else {
        int tidx = qt_g * NS + c;
        float* ap = accP + (size_t)tidx * 2048;
#pragma unroll
        for (int ht = 0; ht < 4; ht++)
#pragma unroll
            for (int qs = 0; qs < 2; qs++)
#pragma unroll
                for (int r = 0; r < 4; r++)
                    ap[(qs * 16 + lg * 4 + r) * 64 + ht * 16 + lr] = acc[ht][qs][r];
        if (lane < 16) {
#pragma unroll
            for (int qs = 0; qs < 2; qs++) {
                mP[tidx * 32 + qs * 16 + lane] = m[qs];
                lP[tidx * 32 + qs * 16 + lane] = l[qs];
            }
        }
    }
}

// ---------------------------------------------------------------------------
// combine<NS>: out[row][h] = sum_c e^{m_c-M} acc_c / sum_c e^{m_c-M} l_c
// ---------------------------------------------------------------------------
template <int NS>
__global__ __launch_bounds__(256) void combine(const float* __restrict__ accP,
                                               const float* __restrict__ mP,
                                               const float* __restrict__ lP,
                                               float* __restrict__ out) {
    int g = blockIdx.x * 256 + threadIdx.x;  // 0 .. 1M-1
    int h = g & 63;
    int row = g >> 6;       // b*4096 + t
    int b = row >> 12;
    int t = row & 4095;
    int qt = t >> 5;
    int qr = t & 31;
    int qt_g = qt * 4 + b;

    float mc[NS];
    float M = -1e30f;
#pragma unroll
    for (int c = 0; c < NS; c++) {
        mc[c] = mP[(qt_g * NS + c) * 32 + qr];
        M = fmaxf(M, mc[c]);
    }
    float num = 0.f, den = 0.f;
#pragma unroll
    for (int c = 0; c < NS; c++) {
        float wgt = __expf(mc[c] - M);
        den += wgt * lP[(qt_g * NS + c) * 32 + qr];
        num += wgt * accP[(size_t)(qt_g * NS + c) * 2048 + qr * 64 + h];
    }
    out[g] = num / den;
}

// ---------------------------------------------------------------------------
extern "C" void kernel_launch(void* const* d_in, const int* in_sizes, int n_in,
                              void* d_out, int out_size, void* d_ws, size_t ws_size,
                              hipStream_t stream) {
    const float* x  = (const float*)d_in[0];
    const float* Wq = (const float*)d_in[1];
    const float* Wk = (const float*)d_in[2];
    const float* Wv = (const float*)d_in[3];
    float* out = (float*)d_out;

    char* ws = (char*)d_ws;
    unsigned short* Qs = (unsigned short*)(ws);                   // 2 MB @ 0
    unsigned short* Ks = (unsigned short*)(ws + (2u << 20));      // 2 MB @ 2M
    unsigned short* Vt = (unsigned short*)(ws + (4u << 20));      // 2 MB @ 4M
    unsigned short* Wt = (unsigned short*)(ws + (6u << 20));      // 384 KB @ 6M
    float* accP = (float*)(ws + (8u << 20));                      // 16 MB @ 8M
    float* mP   = (float*)(ws + (24u << 20));                     // 256 KB @ 24M
    float* lP   = (float*)(ws + (24u << 20) + (256u << 10));      // 256 KB

    prep_w<<<768, 256, 0, stream>>>(Wq, Wk, Wv, Wt);
    projt<<<512, 256, 0, stream>>>(x, Wt, Qs, Ks, Vt);

    if (ws_size >= (25u << 20)) {
        attn<4><<<2048, 64, 0, stream>>>(Qs, Ks, Vt, out, accP, mP, lP);
        combine<4><<<4096, 256, 0, stream>>>(accP, mP, lP, out);
    } else {
        attn<1><<<512, 64, 0, stream>>>(Qs, Ks, Vt, out, accP, mP, lP);
    }
}

// Round 12
// 104.283 us; speedup vs baseline: 1.8507x; 1.0261x over previous
//
#include <hip/hip_runtime.h>
#include <hip/hip_bf16.h>

typedef __attribute__((ext_vector_type(8))) short short8;
typedef __attribute__((ext_vector_type(4))) float f32x4;

#define MFMA16(a, b, c) __builtin_amdgcn_mfma_f32_16x16x32_bf16((a), (b), (c), 0, 0, 0)

// async global->LDS, 16B per lane; dest is wave-uniform base + lane*16
typedef const __attribute__((address_space(1))) unsigned int* gas_t;
typedef __attribute__((address_space(3))) unsigned int* las_t;
#define GLDS16(g, l) __builtin_amdgcn_global_load_lds((gas_t)(g), (las_t)(l), 16, 0, 0)

// scalar round-to-nearest-even f32 -> bf16 bits (proven rounds 1/3/6)
__device__ inline unsigned short f2bf(float f) {
    union { float f; unsigned int u; } v;
    v.f = f;
    unsigned int u = v.u;
    return (unsigned short)((u + 0x7fffu + ((u >> 16) & 1u)) >> 16);
}

// ---------------------------------------------------------------------------
// Wt[n][c] bf16, n in [0,192): 0..63 Wq (pre-scaled 1/8), 64..127 Wk, 128..191 Wv
// ---------------------------------------------------------------------------
__global__ __launch_bounds__(256) void prep_w(const float* __restrict__ Wq,
                                              const float* __restrict__ Wk,
                                              const float* __restrict__ Wv,
                                              unsigned short* __restrict__ Wt) {
    int idx = blockIdx.x * 256 + threadIdx.x;
    if (idx >= 192 * 1024) return;
    int n = idx >> 10;
    int c = idx & 1023;
    const float* W = (n < 64) ? Wq : ((n < 128) ? Wk : Wv);
    float v = W[c * 64 + (n & 63)];
    if (n < 64) v *= 0.125f;  // fold 1/sqrt(head_size) into Wq
    Wt[idx] = f2bf(v);
}

// ---------------------------------------------------------------------------
// projt: LDS-staged projection, 1024 blocks (4/CU, ALL resident -> barrier
// drains overlap across desynchronized blocks). Tile 16 rows x 192 cols,
// BK=128, double-buffered 8KB x-tile via global_load_lds. 16B slots
// XOR-swizzled (slot ^ (row&7)) on BOTH source and ds_read (involution).
// Wave w owns cols [w*48, w*48+48) = 3 accumulators.
// ---------------------------------------------------------------------------
__global__ __launch_bounds__(256, 4) void projt(const float* __restrict__ x,
                                                const unsigned short* __restrict__ Wt,
                                                unsigned short* __restrict__ Qs,
                                                unsigned short* __restrict__ Ks,
                                                unsigned short* __restrict__ Vt) {
    __shared__ __align__(16) float xbuf[2][16 * 128];      // 2 x 8 KB dbuf
    __shared__ __align__(16) unsigned short vt_l[64][16];  // 2 KB V transpose

    const int tid = threadIdx.x;
    const int w = tid >> 6;
    const int lane = tid & 63;
    const int lr = lane & 15;
    const int lg = lane >> 4;
    const int t0 = blockIdx.x * 16;
    const int nbase = w * 48;

    f32x4 acc[3];
#pragma unroll
    for (int i = 0; i < 3; i++) acc[i] = (f32x4){0.f, 0.f, 0.f, 0.f};

    const unsigned short* wbase = Wt + (size_t)(nbase + lr) * 1024 + lg * 8;

    // wave w stages rows [w*4, w*4+4): 2 calls x 1KB (2 rows each; 512B/row).
    // LDS slot sl (16B) of row holds global chunk sl^(row&7).
#define STAGE_X(buf, c0)                                                       \
    {                                                                          \
        _Pragma("unroll")                                                      \
        for (int p = 0; p < 2; p++) {                                          \
            int row = w * 4 + p * 2 + (lane >> 5);                             \
            int chunk = (lane & 31) ^ (row & 7);                               \
            const float* src = x + (size_t)(t0 + row) * 1024 + (c0) + chunk * 4;\
            float* dst = &xbuf[buf][(w * 4 + p * 2) * 128]; /* wave-uniform */ \
            GLDS16(src, dst);                                                  \
        }                                                                      \
    }

    STAGE_X(0, 0);
    __syncthreads();

    int cur = 0;
    for (int t = 0; t < 8; ++t) {
        if (t < 7) STAGE_X(cur ^ 1, (t + 1) * 128);

        const int c0 = t * 128;
        const char* xb = (const char*)&xbuf[cur][0];
#pragma unroll
        for (int h = 0; h < 4; h++) {
            short8 bfr[3];
#pragma unroll
            for (int nt = 0; nt < 3; nt++)
                bfr[nt] = *(const short8*)(wbase + (size_t)nt * 16384 + c0 + h * 32);
            int cb = h * 8 + lg * 2;
            float4 a0 = *(const float4*)(xb + lr * 512 + ((cb) ^ (lr & 7)) * 16);
            float4 a1 = *(const float4*)(xb + lr * 512 + ((cb + 1) ^ (lr & 7)) * 16);
            short8 a;
            a[0] = (short)f2bf(a0.x); a[1] = (short)f2bf(a0.y);
            a[2] = (short)f2bf(a0.z); a[3] = (short)f2bf(a0.w);
            a[4] = (short)f2bf(a1.x); a[5] = (short)f2bf(a1.y);
            a[6] = (short)f2bf(a1.z); a[7] = (short)f2bf(a1.w);
#pragma unroll
            for (int nt = 0; nt < 3; nt++) acc[nt] = MFMA16(a, bfr[nt], acc[nt]);
        }
        __syncthreads();  // drains staging + LDS reads; swap buffers
        cur ^= 1;
    }

    // epilogue (round-6 proven mapping): D col = lr -> n, row = lg*4+r -> t
#pragma unroll
    for (int nt = 0; nt < 3; nt++) {
#pragma unroll
        for (int r = 0; r < 4; r++) {
            int n = nbase + nt * 16 + lr;
            int t = t0 + lg * 4 + r;
            float v = acc[nt][r];
            if (n < 64) {
                Qs[(size_t)t * 64 + n] = f2bf(v);
            } else if (n < 128) {
                Ks[(size_t)t * 64 + (n - 64)] = f2bf(v);
            } else {
                vt_l[n - 128][lg * 4 + r] = f2bf(v);
            }
        }
    }
    __syncthreads();
    // cooperative coalesced V^T store: 64 h-rows x 16 t-cols
    {
        int h = tid >> 2;
        int part = tid & 3;
        int b = t0 >> 12;
        int tt0 = t0 & 4095;
        uint2 val = *(const uint2*)&vt_l[h][part * 4];
        *(uint2*)(Vt + (size_t)b * 262144 + (size_t)h * 4096 + tt0 + part * 4) = val;
    }
}

// ---------------------------------------------------------------------------
// attn<NS>: causal flash attention, swapped QK^T (S^T = K*Q), QBLK=32 (2 q-
// subtiles), KVBLK=64, 1 wave/block, KV split into NS chunks.
// ---------------------------------------------------------------------------
#define SROW 72  // P-tile row stride in halfwords (144 B/row)

template <int NS>
__global__ __launch_bounds__(64) void attn(const unsigned short* __restrict__ Qs,
                                           const unsigned short* __restrict__ Ks,
                                           const unsigned short* __restrict__ Vt,
                                           float* __restrict__ out,
                                           float* __restrict__ accP,
                                           float* __restrict__ mP,
                                           float* __restrict__ lP) {
    __shared__ unsigned short pl[32 * SROW];  // 32 q-rows x 64 kv-cols

    const int ntasks = 512 * NS;
    int raw = ntasks - 1 - blockIdx.x;  // longest scans first
    int qt_g = raw / NS;
    int c = raw - qt_g * NS;
    int qt = qt_g >> 2;
    int b = qt_g & 3;
    int q0 = qt * 32;

    int lane = threadIdx.x;
    int lr = lane & 15;
    int lg = lane >> 4;

    const unsigned short* Qb = Qs + (size_t)b * 262144;
    const unsigned short* Kb = Ks + (size_t)b * 262144;
    const unsigned short* Vb = Vt + (size_t)b * 262144;

    short8 qf[2][2];
#pragma unroll
    for (int qs = 0; qs < 2; qs++)
#pragma unroll
        for (int kh = 0; kh < 2; kh++)
            qf[qs][kh] = *(const short8*)(Qb + (size_t)(q0 + qs * 16 + lr) * 64 +
                                          kh * 32 + lg * 8);

    f32x4 acc[4][2];  // [ht][qs]
#pragma unroll
    for (int i = 0; i < 4; i++)
#pragma unroll
        for (int qs = 0; qs < 2; qs++) acc[i][qs] = (f32x4){0.f, 0.f, 0.f, 0.f};
    float m[2] = {-1e30f, -1e30f}, l[2] = {0.f, 0.f};

    int nt = (q0 + 95) >> 6;  // ceil((q0+32)/64)
    int tb = (c * nt) / NS;
    int te = ((c + 1) * nt) / NS;

    for (int t64 = tb; t64 < te; ++t64) {
        int kv0 = t64 * 64;

        // ---- S^T = K Q : [64kv x 32q]; lane holds kv=t*16+lg*4+r, q=qs*16+lr
        f32x4 s[4][2];
#pragma unroll
        for (int t = 0; t < 4; t++) {
            const unsigned short* kp = Kb + (size_t)(kv0 + t * 16 + lr) * 64 + lg * 8;
            short8 k0 = *(const short8*)(kp);
            short8 k1 = *(const short8*)(kp + 32);
#pragma unroll
            for (int qs = 0; qs < 2; qs++) {
                f32x4 z = (f32x4){0.f, 0.f, 0.f, 0.f};
                z = MFMA16(k0, qf[qs][0], z);
                z = MFMA16(k1, qf[qs][1], z);
                s[t][qs] = z;
            }
        }

        // ---- issue V loads early (consumed after softmax) ----
        short8 vf[4][2];
#pragma unroll
        for (int ht = 0; ht < 4; ht++)
#pragma unroll
            for (int half = 0; half < 2; half++)
                vf[ht][half] = *(const short8*)(Vb + (size_t)(ht * 16 + lr) * 4096 +
                                                kv0 + half * 32 + lg * 8);

        // ---- causal mask (only the straddling tile needs it) ----
        if (kv0 + 63 > q0) {
#pragma unroll
            for (int t = 0; t < 4; t++)
#pragma unroll
                for (int qs = 0; qs < 2; qs++)
#pragma unroll
                    for (int r = 0; r < 4; r++) {
                        int kv = kv0 + t * 16 + lg * 4 + r;
                        if (kv > q0 + qs * 16 + lr) s[t][qs][r] = -1e30f;
                    }
        }

        // ---- online softmax: lane-local over 16 kv, 2 shuffles per reduce ----
        float mx[2] = {-1e30f, -1e30f};
#pragma unroll
        for (int t = 0; t < 4; t++)
#pragma unroll
            for (int qs = 0; qs < 2; qs++)
#pragma unroll
                for (int r = 0; r < 4; r++) mx[qs] = fmaxf(mx[qs], s[t][qs][r]);
        float alpha[2];
#pragma unroll
        for (int qs = 0; qs < 2; qs++) {
            mx[qs] = fmaxf(mx[qs], __shfl_xor(mx[qs], 16));
            mx[qs] = fmaxf(mx[qs], __shfl_xor(mx[qs], 32));
            float mn = fmaxf(m[qs], mx[qs]);
            alpha[qs] = __expf(m[qs] - mn);
            m[qs] = mn;
        }
        float ps[2] = {0.f, 0.f};
#pragma unroll
        for (int t = 0; t < 4; t++)
#pragma unroll
            for (int qs = 0; qs < 2; qs++)
#pragma unroll
                for (int r = 0; r < 4; r++) {
                    float e = __expf(s[t][qs][r] - m[qs]);
                    s[t][qs][r] = e;
                    ps[qs] += e;
                }
#pragma unroll
        for (int qs = 0; qs < 2; qs++) {
            ps[qs] += __shfl_xor(ps[qs], 16);
            ps[qs] += __shfl_xor(ps[qs], 32);
            l[qs] = l[qs] * alpha[qs] + ps[qs];
        }

        // ---- rescale O (row q = qs*16+lg*4+r needs alpha from lane lg*4+r) ----
        float ar[2][4];
#pragma unroll
        for (int qs = 0; qs < 2; qs++)
#pragma unroll
            for (int r = 0; r < 4; r++) ar[qs][r] = __shfl(alpha[qs], lg * 4 + r);
#pragma unroll
        for (int ht = 0; ht < 4; ht++)
#pragma unroll
            for (int qs = 0; qs < 2; qs++)
#pragma unroll
                for (int r = 0; r < 4; r++) acc[ht][qs][r] *= ar[qs][r];

        // ---- pack P -> LDS (transpose to A-fragment layout) ----
#pragma unroll
        for (int qs = 0; qs < 2; qs++)
#pragma unroll
            for (int t = 0; t < 4; t++) {
                uint2 uu;
                uu.x = (unsigned)f2bf(s[t][qs][0]) | ((unsigned)f2bf(s[t][qs][1]) << 16);
                uu.y = (unsigned)f2bf(s[t][qs][2]) | ((unsigned)f2bf(s[t][qs][3]) << 16);
                *(uint2*)&pl[(qs * 16 + lr) * SROW + t * 16 + lg * 4] = uu;
            }
        __syncthreads();
        short8 pa[2][2];
#pragma unroll
        for (int qs = 0; qs < 2; qs++)
#pragma unroll
            for (int half = 0; half < 2; half++)
                pa[qs][half] = *(const short8*)&pl[(qs * 16 + lr) * SROW +
                                                   half * 32 + lg * 8];

        // ---- O += P V ----
#pragma unroll
        for (int ht = 0; ht < 4; ht++)
#pragma unroll
            for (int qs = 0; qs < 2; qs++) {
                acc[ht][qs] = MFMA16(pa[qs][0], vf[ht][0], acc[ht][qs]);
                acc[ht][qs] = MFMA16(pa[qs][1], vf[ht][1], acc[ht][qs]);
            }
        __syncthreads();
    }

    if (NS == 1) {
        float rl[2][4];
#pragma unroll
        for (int qs = 0; qs < 2; qs++)
#pragma unroll
            for (int r = 0; r < 4; r++) rl[qs][r] = 1.0f / __shfl(l[qs], lg * 4 + r);
#pragma unroll
        for (int ht = 0; ht < 4; ht++)
#pragma unroll
            for (int qs = 0; qs < 2; qs++)
#pragma unroll
                for (int r = 0; r < 4; r++) {
                    size_t o = ((size_t)b * 4096 + q0 + qs * 16 + lg * 4 + r) * 64 +
                               ht * 16 + lr;
                    out[o] = acc[ht][qs][r] * rl[qs][r];
                }
    } else {
        int tidx = qt_g * NS + c;
        float* ap = accP + (size_t)tidx * 2048;
#pragma unroll
        for (int ht = 0; ht < 4; ht++)
#pragma unroll
            for (int qs = 0; qs < 2; qs++)
#pragma unroll
                for (int r = 0; r < 4; r++)
                    ap[(qs * 16 + lg * 4 + r) * 64 + ht * 16 + lr] = acc[ht][qs][r];
        if (lane < 16) {
#pragma unroll
            for (int qs = 0; qs < 2; qs++) {
                mP[tidx * 32 + qs * 16 + lane] = m[qs];
                lP[tidx * 32 + qs * 16 + lane] = l[qs];
            }
        }
    }
}

// ---------------------------------------------------------------------------
// combine<NS>: out[row][h] = sum_c e^{m_c-M} acc_c / sum_c e^{m_c-M} l_c
// ---------------------------------------------------------------------------
template <int NS>
__global__ __launch_bounds__(256) void combine(const float* __restrict__ accP,
                                               const float* __restrict__ mP,
                                               const float* __restrict__ lP,
                                               float* __restrict__ out) {
    int g = blockIdx.x * 256 + threadIdx.x;  // 0 .. 1M-1
    int h = g & 63;
    int row = g >> 6;       // b*4096 + t
    int b = row >> 12;
    int t = row & 4095;
    int qt = t >> 5;
    int qr = t & 31;
    int qt_g = qt * 4 + b;

    float mc[NS];
    float M = -1e30f;
#pragma unroll
    for (int c = 0; c < NS; c++) {
        mc[c] = mP[(qt_g * NS + c) * 32 + qr];
        M = fmaxf(M, mc[c]);
    }
    float num = 0.f, den = 0.f;
#pragma unroll
    for (int c = 0; c < NS; c++) {
        float wgt = __expf(mc[c] - M);
        den += wgt * lP[(qt_g * NS + c) * 32 + qr];
        num += wgt * accP[(size_t)(qt_g * NS + c) * 2048 + qr * 64 + h];
    }
    out[g] = num / den;
}

// ---------------------------------------------------------------------------
extern "C" void kernel_launch(void* const* d_in, const int* in_sizes, int n_in,
                              void* d_out, int out_size, void* d_ws, size_t ws_size,
                              hipStream_t stream) {
    const float* x  = (const float*)d_in[0];
    const float* Wq = (const float*)d_in[1];
    const float* Wk = (const float*)d_in[2];
    const float* Wv = (const float*)d_in[3];
    float* out = (float*)d_out;

    char* ws = (char*)d_ws;
    unsigned short* Qs = (unsigned short*)(ws);                   // 2 MB @ 0
    unsigned short* Ks = (unsigned short*)(ws + (2u << 20));      // 2 MB @ 2M
    unsigned short* Vt = (unsigned short*)(ws + (4u << 20));      // 2 MB @ 4M
    unsigned short* Wt = (unsigned short*)(ws + (6u << 20));      // 384 KB @ 6M
    float* accP = (float*)(ws + (8u << 20));                      // 16 MB @ 8M
    float* mP   = (float*)(ws + (24u << 20));                     // 256 KB @ 24M
    float* lP   = (float*)(ws + (24u << 20) + (256u << 10));      // 256 KB

    prep_w<<<768, 256, 0, stream>>>(Wq, Wk, Wv, Wt);
    projt<<<1024, 256, 0, stream>>>(x, Wt, Qs, Ks, Vt);

    if (ws_size >= (25u << 20)) {
        attn<4><<<2048, 64, 0, stream>>>(Qs, Ks, Vt, out, accP, mP, lP);
        combine<4><<<4096, 256, 0, stream>>>(accP, mP, lP, out);
    } else {
        attn<1><<<512, 64, 0, stream>>>(Qs, Ks, Vt, out, accP, mP, lP);
    }
}